// Round 2
// baseline (479.209 us; speedup 1.0000x reference)
//
#include <hip/hip_runtime.h>
#include <stdint.h>

// ---------- types ----------
typedef __bf16 bf16x8 __attribute__((ext_vector_type(8)));
typedef float f32x4 __attribute__((ext_vector_type(4)));

#define N_B 32768
#define S_IN 256
#define H_DIM 512
#define K1_DIM 2304   // 256 * 9, k = i*9 + j
#define K2_DIM 4608   // 512 * 9, k = h*9 + j
#define LDA 296       // padded A-tile row stride in u16 (288 + 8): uniform bank spread

#define MFMA __builtin_amdgcn_mfma_f32_16x16x32_bf16

static __device__ __forceinline__ unsigned short f2bf(float f) {
  union { float f; unsigned u; } v; v.f = f;
  unsigned r = v.u + 0x7fffu + ((v.u >> 16) & 1u);
  return (unsigned short)(r >> 16);
}

// Uniform-knot cardinal cubic B-spline + silu. Produces the 9 feature u16s for one
// scalar x: s16 = bf16(silu(x)); planes 0..7 (spline bases) packed into q0..q3
// (2 planes per u32). Nonzero planes are c-3..c (c = floor(2.5x+5.5)) holding
// w0..w3; placement via 64-bit shift of packed {w0,w1,w2,w3}. Out-of-range planes
// (grid edge) shift out naturally — matches the reference's half-open Cox-de Boor.
static __device__ __forceinline__ void kan_feat(float x, unsigned& s16,
    unsigned& q0, unsigned& q1, unsigned& q2, unsigned& q3) {
  s16 = f2bf(x / (1.f + __expf(-x)));
  float u = fmaf(2.5f, x, 5.5f);
  float cf = floorf(u);
  float f = u - cf;
  float f2 = f * f;
  float f3 = f2 * f;
  const float k6 = 1.f / 6.f;
  float w3v = f3 * k6;
  float w2v = (3.f * (f + f2 - f3) + 1.f) * k6;
  float w1v = (3.f * f3 - 6.f * f2 + 4.f) * k6;
  float omf = 1.f - f;
  float w0v = omf * omf * omf * k6;
  int i0 = (int)cf - 3;
  uint64_t W64 = (uint64_t)((unsigned)f2bf(w0v) | ((unsigned)f2bf(w1v) << 16))
               | ((uint64_t)((unsigned)f2bf(w2v) | ((unsigned)f2bf(w3v) << 16)) << 32);
  uint64_t lo = 0, hi = 0;
  if (i0 >= 0) {
    int s = i0 * 16;
    lo = (i0 < 4) ? (W64 << (s & 63)) : 0;
    uint64_t hr = (i0 >= 1 && i0 < 4) ? (W64 >> ((64 - s) & 63)) : 0;
    uint64_t hl = (i0 >= 4 && i0 < 8) ? (W64 << ((s - 64) & 63)) : 0;
    hi = hr | hl;
  } else {
    lo = (i0 >= -3) ? (W64 >> ((-i0 * 16) & 63)) : 0;
  }
  q0 = (unsigned)lo; q1 = (unsigned)(lo >> 32);
  q2 = (unsigned)hi; q3 = (unsigned)(hi >> 32);
}

// 8 x -> 72 u16 (9 per x, h-major) packed as 36 u32. All indices compile-time.
static __device__ __forceinline__ void feat_pack9(const float* xs, unsigned* o) {
  #pragma unroll
  for (int pe = 0; pe < 4; ++pe) {
    unsigned sA, a0, a1, a2, a3, sB, b0, b1, b2, b3;
    kan_feat(xs[2 * pe], sA, a0, a1, a2, a3);
    kan_feat(xs[2 * pe + 1], sB, b0, b1, b2, b3);
    unsigned* op = o + pe * 9;
    op[0] = sA | (a0 << 16);
    op[1] = (a0 >> 16) | (a1 << 16);
    op[2] = (a1 >> 16) | (a2 << 16);
    op[3] = (a2 >> 16) | (a3 << 16);
    op[4] = (a3 >> 16) | (sB << 16);
    op[5] = b0; op[6] = b1; op[7] = b2; op[8] = b3;
  }
}

// ---------- sentinel (workspace too small diagnostic) ----------
__global__ void k_sentinel(float* out, int n) {
  int i = blockIdx.x * blockDim.x + threadIdx.x;
  for (; i < n; i += gridDim.x * blockDim.x) out[i] = 12345.f;
}

// ---------- weight prep: f32 -> bf16, h-major K layout (k = i*9 + j) ----------
__global__ void k_prep_w1(const float* __restrict__ base_w,
                          const float* __restrict__ spline_w,
                          unsigned short* __restrict__ W1) {
  int idx = blockIdx.x * blockDim.x + threadIdx.x;   // 512*2304
  int n = idx / K1_DIM;
  int k = idx - n * K1_DIM;
  int i = k / 9;
  int j = k - i * 9;
  float v = (j == 0) ? base_w[n * S_IN + i]
                     : spline_w[(size_t)(n * S_IN + i) * 8 + (j - 1)];
  W1[idx] = f2bf(v);
}

__global__ void k_prep_w2(const float* __restrict__ mean_base,
                          const float* __restrict__ mean_spl,
                          const float* __restrict__ lstd_base,
                          const float* __restrict__ lstd_spl,
                          unsigned short* __restrict__ W2) {
  int idx = blockIdx.x * blockDim.x + threadIdx.x;   // 128*4608
  int n = idx / K2_DIM;
  int k = idx - n * K2_DIM;
  int h = k / 9;
  int j = k - h * 9;
  const float* bw = (n < 64) ? mean_base : lstd_base;
  const float* sw = (n < 64) ? mean_spl : lstd_spl;
  int nn = n & 63;
  float v = (j == 0) ? bw[nn * H_DIM + h]
                     : sw[(size_t)(nn * H_DIM + h) * 8 + (j - 1)];
  W2[idx] = f2bf(v);
}

// ---------- GEMM1 (fused feature expansion): X = KAN1(state) ----------
// Block: 64 rows x 128 cols, K1 = 2304 in 8 chunks of 288 (32 inputs x 9 feats).
// A (features) computed in-kernel -> LDS [64][296]; B (W1) global->registers.
__global__ __launch_bounds__(256) void k_gemm1(
    const float* __restrict__ state,
    const unsigned short* __restrict__ W1,
    float* __restrict__ X) {
  extern __shared__ unsigned short At[];
  const int t = threadIdx.x;
  const int bm = blockIdx.x >> 2;        // 0..511
  const int bn = blockIdx.x & 3;         // 0..3
  const int row = t >> 2, quart = t & 3;
  const int wave = t >> 6, lane = t & 63;
  const int wm = (wave & 1) * 32;
  const int wn = (wave >> 1) * 64;
  const int lr = lane & 15;
  const int lk = (lane >> 4) * 8;

  const float* xp = state + (size_t)(bm * 64 + row) * S_IN + quart * 8;

  const unsigned short* bptr[4];
  #pragma unroll
  for (int fn = 0; fn < 4; ++fn)
    bptr[fn] = W1 + (size_t)(bn * 128 + wn + fn * 16 + lr) * K1_DIM + lk;

  f32x4 acc[2][4];
  #pragma unroll
  for (int a = 0; a < 2; ++a)
    #pragma unroll
    for (int b = 0; b < 4; ++b) acc[a][b] = (f32x4){0.f, 0.f, 0.f, 0.f};

  for (int ch = 0; ch < 8; ++ch) {
    __syncthreads();                     // prev chunk's A reads complete
    float xs[8];
    {
      const float4 v0 = *(const float4*)(xp + ch * 32);
      const float4 v1 = *(const float4*)(xp + ch * 32 + 4);
      xs[0] = v0.x; xs[1] = v0.y; xs[2] = v0.z; xs[3] = v0.w;
      xs[4] = v1.x; xs[5] = v1.y; xs[6] = v1.z; xs[7] = v1.w;
    }
    unsigned o[36];
    feat_pack9(xs, o);
    unsigned* dst = (unsigned*)(At + row * LDA + quart * 72);
    #pragma unroll
    for (int i = 0; i < 9; ++i)
      *(uint4*)(dst + 4 * i) = make_uint4(o[4*i], o[4*i+1], o[4*i+2], o[4*i+3]);
    __syncthreads();                     // A tile visible

    const size_t ko = (size_t)ch * 288;
    bf16x8 bb[2][4];
    #pragma unroll
    for (int fn = 0; fn < 4; ++fn)
      bb[0][fn] = *(const bf16x8*)(bptr[fn] + ko);
    #pragma unroll
    for (int ks = 0; ks < 9; ++ks) {
      if (ks < 8) {
        #pragma unroll
        for (int fn = 0; fn < 4; ++fn)
          bb[(ks + 1) & 1][fn] = *(const bf16x8*)(bptr[fn] + ko + (ks + 1) * 32);
      }
      const bf16x8 af0 = *(const bf16x8*)(At + (wm + lr) * LDA + ks * 32 + lk);
      const bf16x8 af1 = *(const bf16x8*)(At + (wm + 16 + lr) * LDA + ks * 32 + lk);
      #pragma unroll
      for (int fn = 0; fn < 4; ++fn) {
        acc[0][fn] = MFMA(af0, bb[ks & 1][fn], acc[0][fn], 0, 0, 0);
        acc[1][fn] = MFMA(af1, bb[ks & 1][fn], acc[1][fn], 0, 0, 0);
      }
    }
  }

  // C/D layout: col = lane&15, row = (lane>>4)*4 + reg
  float* Xb = X + (size_t)(bm * 64) * H_DIM + bn * 128;
  #pragma unroll
  for (int fm = 0; fm < 2; ++fm) {
    const int r0 = wm + fm * 16 + (lane >> 4) * 4;
    #pragma unroll
    for (int fn = 0; fn < 4; ++fn) {
      const int col = wn + fn * 16 + lr;
      #pragma unroll
      for (int r = 0; r < 4; ++r)
        Xb[(size_t)(r0 + r) * H_DIM + col] = acc[fm][fn][r];
    }
  }
}

// ---------- GEMM2 (fused LN+relu+features): heads = KAN2(relu(LN(X))) ----------
// Block: 64 rows x 128 cols (all N), K2 = 4608 in 16 chunks of 288.
__global__ __launch_bounds__(256) void k_gemm2(
    const float* __restrict__ X, const unsigned short* __restrict__ W2,
    const float* __restrict__ gamma, const float* __restrict__ beta,
    float* __restrict__ out) {
  extern __shared__ unsigned short At[];
  const int t = threadIdx.x;
  const int bm = blockIdx.x;             // 0..511
  const int row = t >> 2, quart = t & 3;
  const int wave = t >> 6, lane = t & 63;
  const int wm = (wave & 1) * 32;
  const int wn = (wave >> 1) * 64;
  const int lr = lane & 15;
  const int lk = (lane >> 4) * 8;

  const float* Xrow = X + (size_t)(bm * 64 + row) * H_DIM;

  // row stats: 4 threads per row over 512 elems
  float s = 0.f, ss = 0.f;
  #pragma unroll 4
  for (int q = 0; q < 32; ++q) {
    float4 v = *(const float4*)(Xrow + quart * 128 + q * 4);
    s += v.x + v.y + v.z + v.w;
    ss += v.x * v.x + v.y * v.y + v.z * v.z + v.w * v.w;
  }
  s += __shfl_xor(s, 1); ss += __shfl_xor(ss, 1);
  s += __shfl_xor(s, 2); ss += __shfl_xor(ss, 2);
  const float mu = s * (1.f / 512.f);
  const float var = ss * (1.f / 512.f) - mu * mu;
  const float rstd = rsqrtf(var + 1e-5f);

  const unsigned short* bptr[4];
  #pragma unroll
  for (int fn = 0; fn < 4; ++fn)
    bptr[fn] = W2 + (size_t)(wn + fn * 16 + lr) * K2_DIM + lk;

  f32x4 acc[2][4];
  #pragma unroll
  for (int a = 0; a < 2; ++a)
    #pragma unroll
    for (int b = 0; b < 4; ++b) acc[a][b] = (f32x4){0.f, 0.f, 0.f, 0.f};

  for (int ch = 0; ch < 16; ++ch) {
    __syncthreads();
    const int h0 = ch * 32 + quart * 8;
    float xs[8];
    {
      const float4 xv0 = *(const float4*)(Xrow + h0);
      const float4 xv1 = *(const float4*)(Xrow + h0 + 4);
      const float4 gv0 = *(const float4*)(gamma + h0);
      const float4 gv1 = *(const float4*)(gamma + h0 + 4);
      const float4 bv0 = *(const float4*)(beta + h0);
      const float4 bv1 = *(const float4*)(beta + h0 + 4);
      xs[0] = fmaxf(fmaf((xv0.x - mu) * rstd, gv0.x, bv0.x), 0.f);
      xs[1] = fmaxf(fmaf((xv0.y - mu) * rstd, gv0.y, bv0.y), 0.f);
      xs[2] = fmaxf(fmaf((xv0.z - mu) * rstd, gv0.z, bv0.z), 0.f);
      xs[3] = fmaxf(fmaf((xv0.w - mu) * rstd, gv0.w, bv0.w), 0.f);
      xs[4] = fmaxf(fmaf((xv1.x - mu) * rstd, gv1.x, bv1.x), 0.f);
      xs[5] = fmaxf(fmaf((xv1.y - mu) * rstd, gv1.y, bv1.y), 0.f);
      xs[6] = fmaxf(fmaf((xv1.z - mu) * rstd, gv1.z, bv1.z), 0.f);
      xs[7] = fmaxf(fmaf((xv1.w - mu) * rstd, gv1.w, bv1.w), 0.f);
    }
    unsigned o[36];
    feat_pack9(xs, o);
    unsigned* dst = (unsigned*)(At + row * LDA + quart * 72);
    #pragma unroll
    for (int i = 0; i < 9; ++i)
      *(uint4*)(dst + 4 * i) = make_uint4(o[4*i], o[4*i+1], o[4*i+2], o[4*i+3]);
    __syncthreads();

    const size_t ko = (size_t)ch * 288;
    bf16x8 bb[2][4];
    #pragma unroll
    for (int fn = 0; fn < 4; ++fn)
      bb[0][fn] = *(const bf16x8*)(bptr[fn] + ko);
    #pragma unroll
    for (int ks = 0; ks < 9; ++ks) {
      if (ks < 8) {
        #pragma unroll
        for (int fn = 0; fn < 4; ++fn)
          bb[(ks + 1) & 1][fn] = *(const bf16x8*)(bptr[fn] + ko + (ks + 1) * 32);
      }
      const bf16x8 af0 = *(const bf16x8*)(At + (wm + lr) * LDA + ks * 32 + lk);
      const bf16x8 af1 = *(const bf16x8*)(At + (wm + 16 + lr) * LDA + ks * 32 + lk);
      #pragma unroll
      for (int fn = 0; fn < 4; ++fn) {
        acc[0][fn] = MFMA(af0, bb[ks & 1][fn], acc[0][fn], 0, 0, 0);
        acc[1][fn] = MFMA(af1, bb[ks & 1][fn], acc[1][fn], 0, 0, 0);
      }
    }
  }

  // epilogue: n<64 -> tanh -> mean ; n>=64 -> clip -> log_std (wave-uniform per fn)
  float* mean_out = out;
  float* lstd_out = out + (size_t)N_B * 64;
  #pragma unroll
  for (int fm = 0; fm < 2; ++fm) {
    const int r0 = bm * 64 + wm + fm * 16 + (lane >> 4) * 4;
    #pragma unroll
    for (int fn = 0; fn < 4; ++fn) {
      const int n = wn + fn * 16 + lr;
      #pragma unroll
      for (int r = 0; r < 4; ++r) {
        const float v = acc[fm][fn][r];
        if (n < 64) mean_out[(size_t)(r0 + r) * 64 + n] = tanhf(v);
        else        lstd_out[(size_t)(r0 + r) * 64 + (n - 64)] = fminf(fmaxf(v, -20.f), 2.f);
      }
    }
  }
}

// ---------- launch ----------
extern "C" void kernel_launch(void* const* d_in, const int* in_sizes, int n_in,
                              void* d_out, int out_size, void* d_ws, size_t ws_size,
                              hipStream_t stream) {
  const float* state         = (const float*)d_in[0];
  const float* feat_base_w   = (const float*)d_in[1];
  const float* feat_spline_w = (const float*)d_in[2];
  const float* ln_gamma      = (const float*)d_in[3];
  const float* ln_beta       = (const float*)d_in[4];
  const float* mean_base_w   = (const float*)d_in[5];
  const float* mean_spline_w = (const float*)d_in[6];
  const float* lstd_base_w   = (const float*)d_in[7];
  const float* lstd_spline_w = (const float*)d_in[8];

  // workspace layout (bytes)
  const size_t W1_OFF = 0;               // 512*2304*2  = 2359296
  const size_t W2_OFF = 2359296;         // 128*4608*2  = 1179648
  const size_t X_OFF  = 3538944;         // 32768*512*4 = 67108864
  const size_t NEED   = 70647808;

  if (ws_size < NEED) {
    hipLaunchKernelGGL(k_sentinel, dim3(4096), dim3(256), 0, stream,
                       (float*)d_out, out_size);
    return;
  }

  char* ws = (char*)d_ws;
  unsigned short* W1 = (unsigned short*)(ws + W1_OFF);
  unsigned short* W2 = (unsigned short*)(ws + W2_OFF);
  float* X = (float*)(ws + X_OFF);

  hipLaunchKernelGGL(k_prep_w1, dim3(4608), dim3(256), 0, stream,
                     feat_base_w, feat_spline_w, W1);
  hipLaunchKernelGGL(k_prep_w2, dim3(2304), dim3(256), 0, stream,
                     mean_base_w, mean_spline_w, lstd_base_w, lstd_spline_w, W2);
  hipLaunchKernelGGL(k_gemm1, dim3(2048), dim3(256), 64 * LDA * 2, stream,
                     state, W1, X);
  hipLaunchKernelGGL(k_gemm2, dim3(512), dim3(256), 64 * LDA * 2, stream,
                     X, W2, ln_gamma, ln_beta, (float*)d_out);
}

// Round 11
// 233.598 us; speedup vs baseline: 2.0514x; 2.0514x over previous
//
#include <hip/hip_runtime.h>
#include <stdint.h>

// ---------- types ----------
typedef __bf16 bf16x8 __attribute__((ext_vector_type(8)));
typedef float f32x4 __attribute__((ext_vector_type(4)));
typedef unsigned short u16x8 __attribute__((ext_vector_type(8)));
typedef unsigned int as1_uint __attribute__((address_space(1)));
typedef unsigned int as3_uint __attribute__((address_space(3)));

#define N_B 32768
#define S_IN 256
#define H_DIM 512
#define A_DIM 64
#define K1_DIM 2304   // 9 * 256, k = j*256 + i  (j-major, round-1-validated)
#define K2_DIM 4608   // 9 * 512, k = j*512 + h
#define LDA2 72       // gemm2 A-tile u16 stride (padded 64+8): 36 dw === 4 mod 32, free

#define MFMA __builtin_amdgcn_mfma_f32_16x16x32_bf16

static __device__ __forceinline__ unsigned short f2bf(float f) {
  union { float f; unsigned u; } v; v.f = f;
  unsigned r = v.u + 0x7fffu + ((v.u >> 16) & 1u);
  return (unsigned short)(r >> 16);
}

static __device__ __forceinline__ void gload_lds16(const void* g, void* l) {
  __builtin_amdgcn_global_load_lds((const as1_uint*)g, (as3_uint*)l, 16, 0, 0);
}

// 16B-slot swizzle within each 64-u16 K-window, keyed on tile row low bits.
// Involution: stored[c] = logical[swz(c,row)]; readers XOR the slot the same way.
static __device__ __forceinline__ int swz64(int c, int row) {
  return (c & ~63) | ((((c >> 3) & 7) ^ (row & 7)) << 3) | (c & 7);
}

// Uniform-knot cardinal cubic B-spline (validated r1/r2, absmax 0.0625).
static __device__ __forceinline__ void bspline_w(float x, float& c,
    float& w0, float& w1, float& w2, float& w3) {
  float u = fmaf(2.5f, x, 5.5f);
  c = floorf(u);
  float f = u - c;
  float f2 = f * f;
  float f3 = f2 * f;
  const float k6 = 1.f / 6.f;
  w3 = f3 * k6;
  w2 = (3.f * (f + f2 - f3) + 1.f) * k6;
  w1 = (3.f * f3 - 6.f * f2 + 4.f) * k6;
  float omf = 1.f - f;
  w0 = omf * omf * omf * k6;
}

static __device__ __forceinline__ float silu_f(float x) {
  return x / (1.f + __expf(-x));
}

// ---------- sentinel (workspace too small diagnostic) ----------
__global__ void k_sentinel(float* out, int n) {
  int i = blockIdx.x * blockDim.x + threadIdx.x;
  for (; i < n; i += gridDim.x * blockDim.x) out[i] = 12345.f;
}

// ---------- weight prep: f32 -> bf16, j-major K, pre-swizzled 16B slots ----------
__global__ void k_prep_w1(const float* __restrict__ base_w,
                          const float* __restrict__ spline_w,
                          unsigned short* __restrict__ W1) {
  int idx = blockIdx.x * blockDim.x + threadIdx.x;   // 512*2304
  int n = idx / K1_DIM;
  int c = idx - n * K1_DIM;          // stored col
  int k = swz64(c, n);               // logical col
  int j = k >> 8;
  int i = k & 255;
  float v = (j == 0) ? base_w[n * S_IN + i]
                     : spline_w[(size_t)(n * S_IN + i) * 8 + (j - 1)];
  W1[idx] = f2bf(v);
}

__global__ void k_prep_w2(const float* __restrict__ mean_base,
                          const float* __restrict__ mean_spl,
                          const float* __restrict__ lstd_base,
                          const float* __restrict__ lstd_spl,
                          unsigned short* __restrict__ W2) {
  int idx = blockIdx.x * blockDim.x + threadIdx.x;   // 128*4608
  int n = idx / K2_DIM;
  int c = idx - n * K2_DIM;
  int k = swz64(c, n);
  int j = k / 512;
  int h = k - j * 512;
  const float* bw = (n < 64) ? mean_base : lstd_base;
  const float* sw = (n < 64) ? mean_spl : lstd_spl;
  int nn = n & 63;
  float v = (j == 0) ? bw[nn * H_DIM + h]
                     : sw[(size_t)(nn * H_DIM + h) * 8 + (j - 1)];
  W2[idx] = f2bf(v);
}

// ---------- layer-1 features: state[B][256] -> F1[B][2304] bf16 (swizzled) ----------
__global__ void k_features1(const float* __restrict__ state,
                            unsigned short* __restrict__ F1) {
  int tid = blockIdx.x * blockDim.x + threadIdx.x;   // < 2097152
  int base = tid * 4;
  int b = base >> 8;
  int i = base & 255;
  const float4 xv = *(const float4*)(state + base);
  float xs[4] = {xv.x, xv.y, xv.z, xv.w};
  unsigned short outj[9][4];
  #pragma unroll
  for (int e = 0; e < 4; ++e) {
    float x = xs[e];
    float c, w0, w1, w2, w3;
    bspline_w(x, c, w0, w1, w2, w3);
    outj[0][e] = f2bf(silu_f(x));
    #pragma unroll
    for (int g = 0; g < 8; ++g) {
      float d = c - (float)g;
      float v = 0.f;
      v = (d == 0.f) ? w3 : v;
      v = (d == 1.f) ? w2 : v;
      v = (d == 2.f) ? w1 : v;
      v = (d == 3.f) ? w0 : v;
      outj[g + 1][e] = f2bf(v);
    }
  }
  size_t rowbase = (size_t)b * K1_DIM;
  #pragma unroll
  for (int j = 0; j < 9; ++j) {
    // 8B write stays inside its 16B slot (i%8 in {0,4}); swizzle the slot.
    int c = swz64(j * S_IN + i, b);
    *(ushort4*)(F1 + rowbase + c) =
        make_ushort4(outj[j][0], outj[j][1], outj[j][2], outj[j][3]);
  }
}

// ---------- GEMM1: X[32768][512] = F1 @ W1^T  (round-1 skeleton) ----------
// 128x128 tile, BK=64, double-buffered global_load_lds(16B), 4 waves.
__global__ __launch_bounds__(256, 2) void k_gemm1(
    const unsigned short* __restrict__ F1,
    const unsigned short* __restrict__ W1,
    float* __restrict__ X) {
  extern __shared__ unsigned short smem[];
  unsigned short* As0 = smem;            // [128][64] swizzled image
  unsigned short* As1 = smem + 8192;
  unsigned short* Bs0 = smem + 16384;
  unsigned short* Bs1 = smem + 24576;

  const int t = threadIdx.x;
  // XCD-aware bijective swizzle (grid 1024 === 0 mod 8): the 4 bn-tiles of a
  // bm row-panel stay on one XCD's L2 -> F1 panel fetched once per XCD.
  const int bid = (int)(blockIdx.x & 7) * 128 + ((int)blockIdx.x >> 3);
  const int bm = bid >> 2;               // 0..255
  const int bn = bid & 3;                // 0..3

  const unsigned short* Ab = F1 + (size_t)bm * 128 * K1_DIM;
  const unsigned short* Bb = W1 + (size_t)bn * 128 * K1_DIM;

  const int srow = t >> 3;               // 0..31
  const int scol = (t & 7) * 8;          // 16B chunks

  auto stage = [&](int buf, int kt) {
    unsigned short* Ad = buf ? As1 : As0;
    unsigned short* Bd = buf ? Bs1 : Bs0;
    const size_t k0 = (size_t)kt * 64;
    #pragma unroll
    for (int q = 0; q < 4; ++q) {
      const int r = q * 32 + srow;
      gload_lds16(Ab + (size_t)r * K1_DIM + k0 + scol, Ad + r * 64 + scol);
      gload_lds16(Bb + (size_t)r * K1_DIM + k0 + scol, Bd + r * 64 + scol);
    }
  };

  const int wave = t >> 6;
  const int lane = t & 63;
  const int wm = (wave >> 1) * 64;
  const int wn = (wave & 1) * 64;
  const int lr = lane & 15;
  const int l4 = lane >> 4;

  f32x4 acc[4][4];
  #pragma unroll
  for (int i = 0; i < 4; ++i)
    #pragma unroll
    for (int jj = 0; jj < 4; ++jj)
      acc[i][jj] = (f32x4){0.f, 0.f, 0.f, 0.f};

  stage(0, 0);
  __syncthreads();
  int cur = 0;
  const int NT = K1_DIM / 64;            // 36
  for (int kt = 0; kt < NT; ++kt) {
    if (kt + 1 < NT) stage(cur ^ 1, kt + 1);
    const unsigned short* A0 = cur ? As1 : As0;
    const unsigned short* B0 = cur ? Bs1 : Bs0;
    #pragma unroll
    for (int ks = 0; ks < 2; ++ks) {
      bf16x8 af[4], bfv[4];
      #pragma unroll
      for (int fm = 0; fm < 4; ++fm) {
        const int r = wm + fm * 16 + lr;
        const int slot = (ks * 4 + l4) ^ (r & 7);
        af[fm] = *(const bf16x8*)(A0 + r * 64 + slot * 8);
      }
      #pragma unroll
      for (int fn = 0; fn < 4; ++fn) {
        const int r = wn + fn * 16 + lr;
        const int slot = (ks * 4 + l4) ^ (r & 7);
        bfv[fn] = *(const bf16x8*)(B0 + r * 64 + slot * 8);
      }
      #pragma unroll
      for (int fm = 0; fm < 4; ++fm)
        #pragma unroll
        for (int fn = 0; fn < 4; ++fn)
          acc[fm][fn] = MFMA(af[fm], bfv[fn], acc[fm][fn], 0, 0, 0);
    }
    __syncthreads();
    cur ^= 1;
  }

  // C/D layout: col = lane&15, row = (lane>>4)*4 + reg
  float* Xb = X + (size_t)bm * 128 * H_DIM + bn * 128;
  #pragma unroll
  for (int fm = 0; fm < 4; ++fm) {
    const int row0 = wm + fm * 16 + l4 * 4;
    #pragma unroll
    for (int fn = 0; fn < 4; ++fn) {
      const int col = wn + fn * 16 + lr;
      #pragma unroll
      for (int r = 0; r < 4; ++r)
        Xb[(size_t)(row0 + r) * H_DIM + col] = acc[fm][fn][r];
    }
  }
}

// ---------- GEMM2 (fused LN+relu+features, round-1 skeleton) ----------
// 64 rows x 128 cols, K2 = 4608 (j-major). A padded to stride 72; B swizzled.
__global__ __launch_bounds__(256, 2) void k_gemm2(
    const float* __restrict__ X, const unsigned short* __restrict__ W2,
    const float* __restrict__ gamma, const float* __restrict__ beta,
    float* __restrict__ out) {
  extern __shared__ unsigned short smem2[];
  unsigned short* At = smem2;            // [64][72]
  unsigned short* Bt = smem2 + 64 * LDA2;// [128][64] swizzled image

  const int t = threadIdx.x;
  const int bm = blockIdx.x;             // 0..511
  const int row = t >> 2;                // local row 0..63
  const int quart = t & 3;
  const int wave = t >> 6;
  const int lane = t & 63;
  const int wn = wave * 32;
  const int lr = lane & 15;
  const int l4 = lane >> 4;

  const float* Xrow = X + (size_t)(bm * 64 + row) * H_DIM;

  // row stats (mean/var over 512), 4 threads per row
  float s = 0.f, ss = 0.f;
  #pragma unroll 4
  for (int q = 0; q < 32; ++q) {
    float4 v = *(const float4*)(Xrow + quart * 128 + q * 4);
    s += v.x + v.y + v.z + v.w;
    ss += v.x * v.x + v.y * v.y + v.z * v.z + v.w * v.w;
  }
  s += __shfl_xor(s, 1); ss += __shfl_xor(ss, 1);
  s += __shfl_xor(s, 2); ss += __shfl_xor(ss, 2);
  const float mu = s * (1.f / 512.f);
  const float var = ss * (1.f / 512.f) - mu * mu;
  const float rstd = rsqrtf(var + 1e-5f);

  f32x4 acc[4][2];
  #pragma unroll
  for (int i = 0; i < 4; ++i)
    #pragma unroll
    for (int jj = 0; jj < 2; ++jj)
      acc[i][jj] = (f32x4){0.f, 0.f, 0.f, 0.f};

  float cw[16], w0[16], w1[16], w2[16], w3[16];

  const int sbrow = t >> 3;
  const int sbcol = (t & 7) * 8;

  for (int hb = 0; hb < 8; ++hb) {
    for (int j = 0; j < 9; ++j) {
      __syncthreads();   // prior MFMA reads drained before overwrite
      // stage B tile (swizzled image stages linearly; readers XOR the slot)
      {
        const size_t k0 = (size_t)j * 512 + hb * 64;
        #pragma unroll
        for (int q = 0; q < 4; ++q) {
          const int r = q * 32 + sbrow;
          gload_lds16(W2 + (size_t)r * K2_DIM + k0 + sbcol, Bt + r * 64 + sbcol);
        }
      }
      // stage A tile: features of normalized x (thread owns row, 16 h's)
      unsigned short av[16];
      if (j == 0) {
        #pragma unroll
        for (int c4 = 0; c4 < 4; ++c4) {
          const int h = hb * 64 + quart * 16 + c4 * 4;
          const float4 xv = *(const float4*)(Xrow + h);
          const float4 gv = *(const float4*)(gamma + h);
          const float4 bv = *(const float4*)(beta + h);
          float xa[4] = {xv.x, xv.y, xv.z, xv.w};
          float ga[4] = {gv.x, gv.y, gv.z, gv.w};
          float ba[4] = {bv.x, bv.y, bv.z, bv.w};
          #pragma unroll
          for (int e2 = 0; e2 < 4; ++e2) {
            const int e = c4 * 4 + e2;
            float xn = fmaf((xa[e2] - mu) * rstd, ga[e2], ba[e2]);
            xn = fmaxf(xn, 0.f);                 // relu
            bspline_w(xn, cw[e], w0[e], w1[e], w2[e], w3[e]);
            av[e] = f2bf(silu_f(xn));
          }
        }
      } else {
        const float g = (float)(j - 1);
        #pragma unroll
        for (int e = 0; e < 16; ++e) {
          const float d = cw[e] - g;
          float v = 0.f;
          v = (d == 0.f) ? w3[e] : v;
          v = (d == 1.f) ? w2[e] : v;
          v = (d == 2.f) ? w1[e] : v;
          v = (d == 3.f) ? w0[e] : v;
          av[e] = f2bf(v);
        }
      }
      u16x8 p0, p1;
      #pragma unroll
      for (int e = 0; e < 8; ++e) { p0[e] = av[e]; p1[e] = av[e + 8]; }
      *(u16x8*)(At + row * LDA2 + quart * 16) = p0;
      *(u16x8*)(At + row * LDA2 + quart * 16 + 8) = p1;

      __syncthreads();   // drains gload_lds (vmcnt) + ds_writes (lgkm)

      #pragma unroll
      for (int ks = 0; ks < 2; ++ks) {
        bf16x8 af[4], bfv[2];
        #pragma unroll
        for (int fm = 0; fm < 4; ++fm)
          af[fm] = *(const bf16x8*)(At + (fm * 16 + lr) * LDA2 + ks * 32 + l4 * 8);
        #pragma unroll
        for (int fn = 0; fn < 2; ++fn) {
          const int r = wn + fn * 16 + lr;
          const int slot = (ks * 4 + l4) ^ (r & 7);
          bfv[fn] = *(const bf16x8*)(Bt + r * 64 + slot * 8);
        }
        #pragma unroll
        for (int fm = 0; fm < 4; ++fm)
          #pragma unroll
          for (int fn = 0; fn < 2; ++fn)
            acc[fm][fn] = MFMA(af[fm], bfv[fn], acc[fm][fn], 0, 0, 0);
      }
    }
  }

  // epilogue: cols 0..63 -> tanh -> mean ; 64..127 -> clip -> log_std
  float* mean_out = out;
  float* lstd_out = out + (size_t)N_B * A_DIM;
  #pragma unroll
  for (int fm = 0; fm < 4; ++fm) {
    const int r0 = bm * 64 + fm * 16 + l4 * 4;
    #pragma unroll
    for (int fn = 0; fn < 2; ++fn) {
      const int n = wn + fn * 16 + lr;
      #pragma unroll
      for (int r = 0; r < 4; ++r) {
        const float v = acc[fm][fn][r];
        if (n < 64) mean_out[(size_t)(r0 + r) * 64 + n] = tanhf(v);
        else lstd_out[(size_t)(r0 + r) * 64 + (n - 64)] = fminf(fmaxf(v, -20.f), 2.f);
      }
    }
  }
}

// ---------- launch ----------
extern "C" void kernel_launch(void* const* d_in, const int* in_sizes, int n_in,
                              void* d_out, int out_size, void* d_ws, size_t ws_size,
                              hipStream_t stream) {
  const float* state         = (const float*)d_in[0];
  const float* feat_base_w   = (const float*)d_in[1];
  const float* feat_spline_w = (const float*)d_in[2];
  const float* ln_gamma      = (const float*)d_in[3];
  const float* ln_beta       = (const float*)d_in[4];
  const float* mean_base_w   = (const float*)d_in[5];
  const float* mean_spline_w = (const float*)d_in[6];
  const float* lstd_base_w   = (const float*)d_in[7];
  const float* lstd_spline_w = (const float*)d_in[8];

  // workspace layout (bytes) — identical to the round-1 run that passed
  const size_t W1_OFF = 0;               // 512*2304*2  = 2359296
  const size_t W2_OFF = 2359296;         // 128*4608*2  = 1179648
  const size_t F1_OFF = 3538944;         // 32768*2304*2 = 150994944
  const size_t X_OFF  = 154533888;       // 32768*512*4 = 67108864
  const size_t NEED   = 221642752;

  if (ws_size < NEED) {
    hipLaunchKernelGGL(k_sentinel, dim3(4096), dim3(256), 0, stream,
                       (float*)d_out, out_size);
    return;
  }

  char* ws = (char*)d_ws;
  unsigned short* W1 = (unsigned short*)(ws + W1_OFF);
  unsigned short* W2 = (unsigned short*)(ws + W2_OFF);
  unsigned short* F1 = (unsigned short*)(ws + F1_OFF);
  float* X = (float*)(ws + X_OFF);

  hipLaunchKernelGGL(k_prep_w1, dim3(4608), dim3(256), 0, stream,
                     feat_base_w, feat_spline_w, W1);
  hipLaunchKernelGGL(k_prep_w2, dim3(2304), dim3(256), 0, stream,
                     mean_base_w, mean_spline_w, lstd_base_w, lstd_spline_w, W2);
  hipLaunchKernelGGL(k_features1, dim3(8192), dim3(256), 0, stream, state, F1);
  hipLaunchKernelGGL(k_gemm1, dim3(1024), dim3(256), 65536, stream, F1, W1, X);
  hipLaunchKernelGGL(k_gemm2, dim3(512), dim3(256), (64 * LDA2 + 128 * 64) * 2,
                     stream, X, W2, ln_gamma, ln_beta, (float*)d_out);
}